// Round 19
// baseline (1668.776 us; speedup 1.0000x reference)
//
#include <hip/hip_runtime.h>
#include <hip/hip_bf16.h>
#include <cstdint>

#define T_LEN 512
#define BATCH 128
#define EMBD 256
#define NCLS 25
#define PADTOK 1
#define CHUNK 64
#define NCHUNK 8

#define N_WPERM (2*4*16*8*64*8)   /* 524288: wih bf16 elems / whh i8 bytes */
#define N_WE (2*2*4*64*16)        /* 16384 i8 bytes */
#define N_BIAS (2*1024)

typedef float f32x4 __attribute__((ext_vector_type(4)));
typedef short s16x8 __attribute__((ext_vector_type(8)));
typedef unsigned int u32x4 __attribute__((ext_vector_type(4)));
typedef int i32x4 __attribute__((ext_vector_type(4)));

#define LOG2E 1.4426950408889634f
#define INV4096 (1.f/4096.f)
#define INV4096_LOG2E (1.4426950408889634f/4096.f)
#define NEG2LOG2E (-2.8853900817779268f)

__device__ __forceinline__ unsigned short f2bf(float f) {
  unsigned int u = __builtin_bit_cast(unsigned int, f);
  unsigned int r = (u + 0x7FFFu + ((u >> 16) & 1u)) >> 16;
  return (unsigned short)r;
}
__device__ __forceinline__ signed char f2i8(float v) {
  float r = fminf(fmaxf(v, -127.f), 127.f);
  return (signed char)__float2int_rn(r);
}
// fast sigmoid/tanh helpers: input already in log2 domain (x2 = x*log2e)
__device__ __forceinline__ float sig2(float x2) {
  return __builtin_amdgcn_rcpf(1.f + __builtin_amdgcn_exp2f(-x2));
}
__device__ __forceinline__ float tanh2(float x2) {
  return 2.f*__builtin_amdgcn_rcpf(1.f + __builtin_amdgcn_exp2f(-2.f*x2)) - 1.f;
}

// ---------------- prep: fragment-order weight permutes + bias sum ----------
// wih (bf16, xg 4-wave): o = ((((d*4+w)*8+kt)*16+s)*64+l)*8+e
// whh (i8 x64, K64 16B): o = ((((d*8+w)*4+kq)*8+s)*64+l)*16 + p
// we  (i8 x64, K64 16B): o = (((d*2+nt)*4+kq)*64+l)*16 + p
__global__ void prep_kernel(const float* wih_f, const float* whh_f,
                            const float* bih_f, const float* bhh_f,
                            const float* wih_b, const float* whh_b,
                            const float* bih_b, const float* bhh_b,
                            const float* W_e,
                            unsigned short* wih_p, signed char* whh_p,
                            signed char* we_p, float* bias)
{
  long total = 2L*N_WPERM + N_WE + N_BIAS;
  for (long i = (long)blockIdx.x*blockDim.x + threadIdx.x; i < total;
       i += (long)gridDim.x*blockDim.x) {
    long j = i;
    if (j < N_WPERM) {           // wih, bf16, 4-wave layout
      int o = (int)j;
      int e = o & 7, l = (o>>3)&63, s = (o>>9)&15, kt = (o>>13)&7, w = (o>>16)&3, d = (o>>18)&1;
      int n = (s>>2)*256 + w*64 + (s&3)*16 + (l & 15);
      int kk = kt*32 + (l>>4)*8 + e;
      const float* src = d ? wih_b : wih_f;
      wih_p[o] = f2bf(src[n*256 + kk]);
      continue;
    }
    j -= N_WPERM;
    if (j < N_WPERM) {           // whh, i8 x64, K64 lane-16B layout
      int o = (int)j;
      int p = o & 15, l = (o>>4)&63, s = (o>>10)&7, kq = (o>>13)&3, w = (o>>15)&7, d = (o>>18)&1;
      int lm = l & 15, lg = l >> 4;
      int n = (s>>1)*256 + w*32 + (s&1)*16 + lm;
      int kk = kq*64 + lg*16 + p;
      const float* src = d ? whh_b : whh_f;
      whh_p[o] = f2i8(src[n*256 + kk] * 64.f);
      continue;
    }
    j -= N_WPERM;
    if (j < N_WE) {              // W_e, i8 x64, K64 lane-16B layout
      int o = (int)j;
      int p = o & 15, l = (o>>4)&63, kq = (o>>10)&3, nt = (o>>12)&1, d = (o>>13)&1;
      int lm = l & 15, lg = l >> 4;
      int cc = nt*16 + lm;
      int kk = kq*64 + lg*16 + p;
      we_p[o] = (cc < NCLS) ? f2i8(W_e[cc*512 + d*256 + kk] * 64.f) : (signed char)0;
      continue;
    }
    j -= N_WE;
    { int o = (int)j; int d = o>>10; int g = o & 1023;
      bias[o] = d ? (bih_b[g]+bhh_b[g]) : (bih_f[g]+bhh_f[g]); }
  }
}

// ------- xg: (emb[sent] @ W_ih^T + biases) * log2e, permuted bf16 ----------
__global__ __launch_bounds__(256) void xg_kernel(const int* sent, const float* emb,
    const unsigned short* wih_p, const float* bias, unsigned short* xg, int k)
{
  int blk2 = blockIdx.y*256 + blockIdx.x;
  int d = blk2 >> 8;
  int blk = blk2 & 255;
  int u = blk >> 2, q = blk & 3;
  int ss = k*CHUNK + u;
  int t = d ? (T_LEN-1-ss) : ss;
  int tid = threadIdx.x;
  int w = tid >> 6, l = tid & 63, lg = l >> 4, lm = l & 15;

  int tok0 = sent[t*BATCH + q*32 + lm];
  int tok1 = sent[t*BATCH + q*32 + 16 + lm];

  const char* wbase = (const char*)wih_p + ((long)(d*4 + w) << 17);

  f32x4 acc[2][16] = {};
  for (int kt = 0; kt < 8; ++kt) {
    const float* p0 = emb + (long)tok0*256 + kt*32 + lg*8;
    const float* p1 = emb + (long)tok1*256 + kt*32 + lg*8;
    f32x4 q00 = *(const f32x4*)p0, q01 = *(const f32x4*)(p0+4);
    f32x4 q10 = *(const f32x4*)p1, q11 = *(const f32x4*)(p1+4);
    s16x8 a0, a1;
    #pragma unroll
    for (int e = 0; e < 4; ++e) {
      a0[e]   = (short)f2bf(q00[e]); a0[4+e] = (short)f2bf(q01[e]);
      a1[e]   = (short)f2bf(q10[e]); a1[4+e] = (short)f2bf(q11[e]);
    }
    #pragma unroll
    for (int s = 0; s < 16; ++s) {
      s16x8 bf = *(const s16x8*)(wbase + (((kt*16 + s) << 10) + (l << 4)));
      acc[0][s] = __builtin_amdgcn_mfma_f32_16x16x32_bf16(a0, bf, acc[0][s], 0,0,0);
      acc[1][s] = __builtin_amdgcn_mfma_f32_16x16x32_bf16(a1, bf, acc[1][s], 0,0,0);
    }
  }
  float bsv[16];
  #pragma unroll
  for (int s = 0; s < 16; ++s) {
    int n = (s>>2)*256 + w*64 + (s&3)*16 + lm;
    bsv[s] = bias[d*1024 + n];
  }
  #pragma unroll
  for (int mt = 0; mt < 2; ++mt) {
    int nb = q*2 + mt;
    char* base = (char*)xg + (((((long)d*CHUNK + u)*8 + nb)*4 + w)*64 + l)*128;
    #pragma unroll
    for (int qq = 0; qq < 8; ++qq) {
      u32x4 pk;
      #pragma unroll
      for (int h2 = 0; h2 < 4; ++h2) {
        int j0 = qq*8 + h2*2;
        unsigned short v0 = f2bf((acc[mt][j0>>2][j0&3] + bsv[j0>>2]) * LOG2E);
        unsigned short v1 = f2bf((acc[mt][(j0+1)>>2][(j0+1)&3] + bsv[(j0+1)>>2]) * LOG2E);
        pk[h2] = (unsigned)v0 | ((unsigned)v1 << 16);
      }
      *(u32x4*)(base + qq*16) = pk;
    }
  }
}

// ---------------- lstm chunk k: clean 16-block dispatch --------------------
// i8 K=64 MFMAs, register-resident W_hh, h double-buffer (1 barrier/step).
__global__ __launch_bounds__(512, 1) void lstm_kernel(
    const unsigned short* xg_rd,
    const signed char* whh_p, const signed char* we_p,
    float* emis_f, float* emis_b, unsigned char* hsave, float* csave, int k)
{
  __shared__ char h_lds[8192];     // 2 x 4KB i8 h buffers, XOR-swizzled

  int id = blockIdx.x, d = id >> 3, nb = id & 7, bbase = nb*16;
  int w = threadIdx.x >> 6, l = threadIdx.x & 63, lg = l >> 4, lm = l & 15;
  float* emis = d ? emis_b : emis_f;
  bool ewave = (w == 0) || (w == 2);   // emission on SIMD0 and SIMD2
  int nte = (w >> 1) & 1;              // 0 for w0, 1 for w2

  // whole W_hh slice in registers: 32 frags x 4 regs = 128 VGPRs
  i32x4 wreg[32];
  const char* wbase = (const char*)whh_p + ((long)(d*8 + w) << 15);
  #pragma unroll
  for (int i = 0; i < 32; ++i)
    wreg[i] = *(const i32x4*)(wbase + (i << 10) + (l << 4));

  // emission weights straight from global (16 KB total, L2-resident)
  i32x4 ewreg[4];
  #pragma unroll
  for (int kq = 0; kq < 4; ++kq)
    ewreg[kq] = *(const i32x4*)((const char*)we_p
        + (((long)(d*2 + nte)*4 + kq) << 10) + (l << 4));

  float c[8];
  if (k == 0) {
    for (int i = threadIdx.x; i < 2048; i += 512) ((unsigned*)h_lds)[i] = 0u;
    #pragma unroll
    for (int i = 0; i < 8; ++i) c[i] = 0.f;
  } else {
    u32x4* hl = (u32x4*)(h_lds + 4096);   // read-buffer of step u=0
    const u32x4* hs = (const u32x4*)(hsave + (long)id*4096);
    if (threadIdx.x < 256) hl[threadIdx.x] = hs[threadIdx.x];
    const float* cs = csave + ((long)id*512 + threadIdx.x)*8;
    #pragma unroll
    for (int i = 0; i < 8; ++i) c[i] = cs[i];
  }
  __syncthreads();

  int prev_t = (k == 0) ? -1 : (d ? (T_LEN - k*CHUNK) : (k*CHUNK - 1));

  for (int u = 0; u < CHUNK; ++u) {
    int ss = k*CHUNK + u;
    int t = d ? (T_LEN-1-ss) : ss;

    // single barrier: prev step's h writes (other buffer) now visible
    asm volatile("s_waitcnt lgkmcnt(0)" ::: "memory");
    __builtin_amdgcn_s_barrier();

    const char* hr = h_lds + (((u & 1) ^ 1) << 12);   // read buffer
    char*       hw = h_lds + ((u & 1) << 12);         // write buffer

    // A-frags: 16 B/lane per K-64 group (one ds_read_b128 each)
    i32x4 a4[4];
    #pragma unroll
    for (int kq = 0; kq < 4; ++kq) {
      int off = (lm*256 + kq*64 + lg*16) ^ ((lm&7)<<4);
      a4[kq] = *(const i32x4*)(hr + off);
    }

    // xg loads (consumed after MFMAs)
    const char* xb = (const char*)xg_rd
        + (((((long)d*CHUNK + u)*8 + nb)*4 + (w>>1))*64 + l)*128 + ((w&1)*16);
    u32x4 xv[4];
    #pragma unroll
    for (int i = 0; i < 4; ++i)
      xv[i] = *(const u32x4*)(xb + i*32);

    // emissions (waves 0,2): 4 i8 MFMAs for previous h
    i32x4 ea = {0,0,0,0};
    if (ewave && prev_t >= 0) {
      #pragma unroll
      for (int kq = 0; kq < 4; ++kq)
        ea = __builtin_amdgcn_mfma_i32_16x16x64_i8(a4[kq], ewreg[kq], ea, 0,0,0);
    }

    // main matvec: 32 i8 MFMAs
    i32x4 acc[8];
    #pragma unroll
    for (int s = 0; s < 8; ++s) acc[s] = (i32x4){0,0,0,0};
    #pragma unroll
    for (int kq = 0; kq < 4; ++kq)
      #pragma unroll
      for (int s = 0; s < 8; ++s)
        acc[s] = __builtin_amdgcn_mfma_i32_16x16x64_i8(a4[kq], wreg[kq*8+s], acc[s], 0,0,0);

    // emissions store (de-scale 1/4096: we x64, h x64)
    if (ewave && prev_t >= 0) {
      int cc = nte*16 + lm;
      if (cc < NCLS) {
        #pragma unroll
        for (int r = 0; r < 4; ++r)
          emis[((long)prev_t*BATCH + bbase + lg*4 + r)*NCLS + cc] = (float)ea[r]*INV4096;
      }
    }

    // xg add; gates emerge in log2 domain (xg pre-scaled by log2e)
    float gf_[8][4];
    #pragma unroll
    for (int s = 0; s < 8; ++s)
      #pragma unroll
      for (int r = 0; r < 4; ++r) {
        unsigned wd = xv[s>>1][(s&1)*2 + (r>>1)];
        unsigned bits = (r&1) ? (wd & 0xffff0000u) : (wd << 16);
        gf_[s][r] = (float)acc[s][r]*INV4096_LOG2E + __builtin_bit_cast(float, bits);
      }

    // nonlinearities (log2-domain, hw rcp/exp2): i,f,g,o at s = q,2+q,4+q,6+q
    #pragma unroll
    for (int q = 0; q < 2; ++q)
      #pragma unroll
      for (int r = 0; r < 4; ++r) {
        float si = sig2(gf_[q][r]);
        float sf = sig2(gf_[2+q][r]);
        float tg = tanh2(gf_[4+q][r]);
        float so = sig2(gf_[6+q][r]);
        float cn = sf*c[q*4+r] + si*tg;
        c[q*4+r] = cn;
        float tc = 2.f*__builtin_amdgcn_rcpf(1.f + __builtin_amdgcn_exp2f(cn*NEG2LOG2E)) - 1.f;
        int m = lg*4 + r;
        int jj = w*32 + q*16 + lm;
        int off = (m*256 + jj) ^ ((m&7)<<4);
        *(signed char*)(hw + off) = (signed char)__float2int_rn(so*tc*64.f);
      }
    prev_t = t;
  }

  asm volatile("s_waitcnt lgkmcnt(0)" ::: "memory");
  __builtin_amdgcn_s_barrier();
  // final h lives in buffer 1 (last write u=63 -> 63&1 = 1)

  if (k == NCHUNK-1) {
    if (ewave) {
      i32x4 a4[4];
      #pragma unroll
      for (int kq = 0; kq < 4; ++kq) {
        int off = (lm*256 + kq*64 + lg*16) ^ ((lm&7)<<4);
        a4[kq] = *(const i32x4*)(h_lds + 4096 + off);
      }
      i32x4 ea = {0,0,0,0};
      #pragma unroll
      for (int kq = 0; kq < 4; ++kq)
        ea = __builtin_amdgcn_mfma_i32_16x16x64_i8(a4[kq], ewreg[kq], ea, 0,0,0);
      int cc = nte*16 + lm;
      if (cc < NCLS) {
        #pragma unroll
        for (int r = 0; r < 4; ++r)
          emis[((long)prev_t*BATCH + bbase + lg*4 + r)*NCLS + cc] = (float)ea[r]*INV4096;
      }
    }
  } else {
    u32x4* hl = (u32x4*)(h_lds + 4096);
    u32x4* hs = (u32x4*)(hsave + (long)id*4096);
    if (threadIdx.x < 256) hs[threadIdx.x] = hl[threadIdx.x];
    float* cs = csave + ((long)id*512 + threadIdx.x)*8;
    #pragma unroll
    for (int i = 0; i < 8; ++i) cs[i] = c[i];
  }
}

// ---------------- emissions fuse: emis_c = emis_f + emis_b + b_e ------------
__global__ __launch_bounds__(256) void efuse_kernel(const float* emis_f,
    const float* emis_b, const float* b_e, float* emis_c)
{
  int i = blockIdx.x*256 + threadIdx.x;
  if (i < T_LEN*BATCH*NCLS)
    emis_c[i] = emis_f[i] + emis_b[i] + b_e[i % NCLS];
}

// ---------------- CRF numerator -------------------------------------------
__global__ void num_kernel(const int* sent, const int* tags, const float* emis_c,
    const float* start_t, const float* end_t, const float* trans, float* num_buf)
{
  int b = blockIdx.x, l = threadIdx.x;   // 64 threads = 1 wave
  float acc = 0.f; int cnt = 0;
  for (int t = l; t < T_LEN; t += 64) {
    int tag = tags[t*BATCH + b];
    float E = emis_c[((long)t*BATCH+b)*NCLS + tag];
    int m = (sent[t*BATCH+b] != PADTOK) ? 1 : 0;
    cnt += m;
    if (t == 0) acc += start_t[tag] + E;
    else if (m) acc += trans[tags[(t-1)*BATCH + b]*NCLS + tag] + E;
  }
  #pragma unroll
  for (int off = 32; off; off >>= 1) { acc += __shfl_xor(acc, off); cnt += __shfl_xor(cnt, off); }
  if (l == 0) num_buf[b] = acc + end_t[tags[(cnt-1)*BATCH + b]];
}

// ---- CRF forward (denominator): readfirstlane ref + readlane/SGPR bcast ---
__global__ __launch_bounds__(64) void denom_kernel(const int* sent, const float* emis_c,
    const float* start_t, const float* end_t, const float* trans,
    const float* num_buf, float* llh)
{
  const float INVLN2 = 1.4426950408889634f;
  const float LN2 = 0.6931471805599453f;
  int l = threadIdx.x;
  bool valid = l < NCLS;
  int j = valid ? l : 0;
  int b = blockIdx.x;                     // 128 blocks, 1 row per wave

  float etr[NCLS];                        // E column j, linear domain
  #pragma unroll
  for (int i = 0; i < NCLS; ++i)
    etr[i] = __builtin_amdgcn_exp2f(trans[i*NCLS + j] * INVLN2);

  float S = (start_t[j] + emis_c[(long)b*NCLS + j]) * INVLN2;

  float e1 = emis_c[((long)1*BATCH + b)*NCLS + j];
  float e2 = emis_c[((long)2*BATCH + b)*NCLS + j];
  int m1 = sent[1*BATCH + b], m2 = sent[2*BATCH + b];

  for (int t = 1; t < T_LEN; ++t) {
    float e0 = e1; int m0 = m1;
    e1 = e2; m1 = m2;
    if (t + 2 < T_LEN) {
      e2 = emis_c[((long)(t+2)*BATCH + b)*NCLS + j];
      m2 = sent[(t+2)*BATCH + b];
    }
    float sref = __builtin_bit_cast(float,
        __builtin_amdgcn_readfirstlane(__builtin_bit_cast(int, S)));
    float qv = __builtin_amdgcn_exp2f(S - sref);
    float accs[5] = {0.f, 0.f, 0.f, 0.f, 0.f};
    #pragma unroll
    for (int i = 0; i < NCLS; ++i) {
      float qi = __builtin_bit_cast(float,
          __builtin_amdgcn_readlane(__builtin_bit_cast(int, qv), i));
      accs[i % 5] = fmaf(qi, etr[i], accs[i % 5]);
    }
    float dot = ((accs[0] + accs[1]) + (accs[2] + accs[3])) + accs[4];
    float nxt = sref + __builtin_amdgcn_logf(dot) + e0 * INVLN2;
    if (m0 != PADTOK) S = nxt;
  }

  float vf = valid ? (S + end_t[j] * INVLN2) : -1e30f;
  float mx = vf;
  #pragma unroll
  for (int off = 32; off; off >>= 1) mx = fmaxf(mx, __shfl_xor(mx, off));
  float ss = valid ? __builtin_amdgcn_exp2f(vf - mx) : 0.f;
  #pragma unroll
  for (int off = 32; off; off >>= 1) ss += __shfl_xor(ss, off);
  if (l == 0) llh[b] = num_buf[b] - (mx + __builtin_amdgcn_logf(ss)) * LN2;
}

__global__ void final_kernel(const float* llh, float* out) {
  __shared__ float red[2];
  int l = threadIdx.x;   // 128
  float v = llh[l];
  #pragma unroll
  for (int off = 32; off; off >>= 1) v += __shfl_xor(v, off);
  if ((l & 63) == 0) red[l >> 6] = v;
  __syncthreads();
  if (l == 0) out[0] = -(red[0] + red[1]);
}

extern "C" void kernel_launch(void* const* d_in, const int* in_sizes, int n_in,
                              void* d_out, int out_size, void* d_ws, size_t ws_size,
                              hipStream_t stream) {
  const int*   sent  = (const int*)d_in[0];
  const int*   tags  = (const int*)d_in[1];
  const float* emb   = (const float*)d_in[2];
  const float* wih_f = (const float*)d_in[3];
  const float* whh_f = (const float*)d_in[4];
  const float* bih_f = (const float*)d_in[5];
  const float* bhh_f = (const float*)d_in[6];
  const float* wih_b = (const float*)d_in[7];
  const float* whh_b = (const float*)d_in[8];
  const float* bih_b = (const float*)d_in[9];
  const float* bhh_b = (const float*)d_in[10];
  const float* W_e   = (const float*)d_in[11];
  const float* b_e   = (const float*)d_in[12];
  const float* st    = (const float*)d_in[13];
  const float* et    = (const float*)d_in[14];
  const float* tr    = (const float*)d_in[15];
  (void)in_sizes; (void)n_in; (void)out_size; (void)ws_size;

  const long SLOT = (long)2*CHUNK*BATCH*1024*2;   // 32 MiB xg slot

  char* ws = (char*)d_ws;
  unsigned short* wih_p  = (unsigned short*)ws; ws += (long)N_WPERM*2;      // 1 MiB
  signed char*    whh_p  = (signed char*)ws;    ws += (long)N_WPERM;        // 512 KiB
  signed char*    we_p   = (signed char*)ws;    ws += (long)N_WE;           // 16 KiB
  float*          bias   = (float*)ws;          ws += (long)N_BIAS*4;       // 8 KiB
  unsigned short* xgr0   = (unsigned short*)ws; ws += SLOT;                 // 32 MiB
  float*          emis_f = (float*)ws;          ws += (long)T_LEN*BATCH*NCLS*4;
  float*          emis_b = (float*)ws;          ws += (long)T_LEN*BATCH*NCLS*4;
  unsigned char*  hsave  = (unsigned char*)ws;  ws += (long)16*4096;
  float*          csave  = (float*)ws;          ws += (long)16*512*8*4;
  float*          numb   = (float*)ws;          ws += 512;
  float*          llh    = (float*)ws;          ws += 512;
  float*          emis_c = (float*)xgr0;        // alias: slot dead after last lstm

  prep_kernel<<<4168, 256, 0, stream>>>(wih_f, whh_f, bih_f, bhh_f,
                                        wih_b, whh_b, bih_b, bhh_b, W_e,
                                        wih_p, whh_p, we_p, bias);
  for (int k = 0; k < NCHUNK; ++k) {
    dim3 g1(256, 2);
    xg_kernel<<<g1, 256, 0, stream>>>(sent, emb, wih_p, bias, xgr0, k);
    lstm_kernel<<<16, 512, 0, stream>>>(xgr0, whh_p, we_p, emis_f, emis_b,
                                        hsave, csave, k);
  }
  efuse_kernel<<<(T_LEN*BATCH*NCLS + 255)/256, 256, 0, stream>>>(emis_f, emis_b, b_e, emis_c);
  num_kernel<<<128, 64, 0, stream>>>(sent, tags, emis_c, st, et, tr, numb);
  denom_kernel<<<128, 64, 0, stream>>>(sent, emis_c, st, et, tr, numb, llh);
  final_kernel<<<1, 128, 0, stream>>>(llh, (float*)d_out);
}

// Round 20
// 1083.416 us; speedup vs baseline: 1.5403x; 1.5403x over previous
//
#include <hip/hip_runtime.h>
#include <hip/hip_bf16.h>
#include <cstdint>

#define T_LEN 512
#define BATCH 128
#define EMBD 256
#define NCLS 25
#define PADTOK 1
#define CHUNK 64
#define NCHUNK 8

#define N_WPERM (2*4*16*8*64*8)   /* 524288: wih bf16 elems / whh i8 bytes */
#define N_WE (2*2*4*64*16)        /* 16384 i8 bytes */
#define N_BIAS (2*1024)

typedef float f32x4 __attribute__((ext_vector_type(4)));
typedef short s16x8 __attribute__((ext_vector_type(8)));
typedef unsigned int u32x4 __attribute__((ext_vector_type(4)));
typedef int i32x4 __attribute__((ext_vector_type(4)));

#define LOG2E 1.4426950408889634f
#define INV4096 (1.f/4096.f)
#define INV4096_LOG2E (1.4426950408889634f/4096.f)
#define NEG2LOG2E (-2.8853900817779268f)

__device__ __forceinline__ unsigned short f2bf(float f) {
  unsigned int u = __builtin_bit_cast(unsigned int, f);
  unsigned int r = (u + 0x7FFFu + ((u >> 16) & 1u)) >> 16;
  return (unsigned short)r;
}
__device__ __forceinline__ signed char f2i8(float v) {
  float r = fminf(fmaxf(v, -127.f), 127.f);
  return (signed char)__float2int_rn(r);
}
// fast sigmoid/tanh helpers: input already in log2 domain (x2 = x*log2e)
__device__ __forceinline__ float sig2(float x2) {
  return __builtin_amdgcn_rcpf(1.f + __builtin_amdgcn_exp2f(-x2));
}
__device__ __forceinline__ float tanh2(float x2) {
  return 2.f*__builtin_amdgcn_rcpf(1.f + __builtin_amdgcn_exp2f(-2.f*x2)) - 1.f;
}

// ---------------- prep: fragment-order weight permutes + bias sum ----------
// wih (bf16, xg):        o = ((((d*4+w4)*8+kt)*16+s)*64+l)*8+e
// whh (i8 x64, 16-wave): o = ((((d*16+w)*4+kq)*4+g)*64+l)*16+p
//                        n = g*256 + w*16 + lm,  kk = kq*64 + lg*16 + p
// we  (i8 x64):          o = (((d*2+nt)*4+kq)*64+l)*16+p
__global__ void prep_kernel(const float* wih_f, const float* whh_f,
                            const float* bih_f, const float* bhh_f,
                            const float* wih_b, const float* whh_b,
                            const float* bih_b, const float* bhh_b,
                            const float* W_e,
                            unsigned short* wih_p, signed char* whh_p,
                            signed char* we_p, float* bias)
{
  long total = 2L*N_WPERM + N_WE + N_BIAS;
  for (long i = (long)blockIdx.x*blockDim.x + threadIdx.x; i < total;
       i += (long)gridDim.x*blockDim.x) {
    long j = i;
    if (j < N_WPERM) {           // wih, bf16
      int o = (int)j;
      int e = o & 7, l = (o>>3)&63, s = (o>>9)&15, kt = (o>>13)&7, w4 = (o>>16)&3, d = (o>>18)&1;
      int n = (s>>2)*256 + w4*64 + (s&3)*16 + (l & 15);
      int kk = kt*32 + (l>>4)*8 + e;
      const float* src = d ? wih_b : wih_f;
      wih_p[o] = f2bf(src[n*256 + kk]);
      continue;
    }
    j -= N_WPERM;
    if (j < N_WPERM) {           // whh, i8 x64, 16-wave layout
      int o = (int)j;
      int p = o & 15, l = (o>>4)&63, g = (o>>10)&3, kq = (o>>12)&3, w = (o>>14)&15, d = (o>>18)&1;
      int lm = l & 15, lg = l >> 4;
      int n = g*256 + w*16 + lm;
      int kk = kq*64 + lg*16 + p;
      const float* src = d ? whh_b : whh_f;
      whh_p[o] = f2i8(src[n*256 + kk] * 64.f);
      continue;
    }
    j -= N_WPERM;
    if (j < N_WE) {              // W_e, i8 x64
      int o = (int)j;
      int p = o & 15, l = (o>>4)&63, kq = (o>>10)&3, nt = (o>>12)&1, d = (o>>13)&1;
      int lm = l & 15, lg = l >> 4;
      int cc = nt*16 + lm;
      int kk = kq*64 + lg*16 + p;
      we_p[o] = (cc < NCLS) ? f2i8(W_e[cc*512 + d*256 + kk] * 64.f) : (signed char)0;
      continue;
    }
    j -= N_WE;
    { int o = (int)j; int d = o>>10; int g = o & 1023;
      bias[o] = d ? (bih_b[g]+bhh_b[g]) : (bih_f[g]+bhh_f[g]); }
  }
}

// ------- xg body (8 waves): round((emb[sent]@W_ih^T + bias)*4096) as i32 ----
// layout per (d,u,nb): 64 KB, i32x4 at ((hb*4+g)*64 + l)*16 + r*4
__device__ __forceinline__ void xg_body(const int* sent, const float* emb,
    const unsigned short* wih_p, const float* bias, int* xg,
    int k, int blk2, int tid)
{
  int d = blk2 >> 8;
  int blk = blk2 & 255;
  int u = blk >> 2, q = blk & 3;
  int ss = k*CHUNK + u;
  int t = d ? (T_LEN-1-ss) : ss;
  int w = tid >> 6, w4 = w & 3, mt = w >> 2;
  int l = tid & 63, lg = l >> 4, lm = l & 15;

  int tok = sent[t*BATCH + q*32 + mt*16 + lm];

  const char* wbase = (const char*)wih_p + ((long)(d*4 + w4) << 17);

  f32x4 acc[16] = {};
  for (int kt = 0; kt < 8; ++kt) {
    const float* p0 = emb + (long)tok*256 + kt*32 + lg*8;
    f32x4 q00 = *(const f32x4*)p0, q01 = *(const f32x4*)(p0+4);
    s16x8 a0;
    #pragma unroll
    for (int e = 0; e < 4; ++e) {
      a0[e] = (short)f2bf(q00[e]); a0[4+e] = (short)f2bf(q01[e]);
    }
    #pragma unroll
    for (int s = 0; s < 16; ++s) {
      s16x8 bf = *(const s16x8*)(wbase + (((kt*16 + s) << 10) + (l << 4)));
      acc[s] = __builtin_amdgcn_mfma_f32_16x16x32_bf16(a0, bf, acc[s], 0,0,0);
    }
  }
  float bsv[16];
  #pragma unroll
  for (int s = 0; s < 16; ++s) {
    int n = (s>>2)*256 + w4*64 + (s&3)*16 + lm;
    bsv[s] = bias[d*1024 + n];
  }
  int nb = q*2 + mt;
  char* base = (char*)xg + (((long)(d*CHUNK + u)*8 + nb) << 16);
  #pragma unroll
  for (int s = 0; s < 16; ++s) {
    int hb = w4*4 + (s&3), g = s>>2;
    i32x4 v;
    #pragma unroll
    for (int r = 0; r < 4; ++r)
      v[r] = __float2int_rn((acc[s][r] + bsv[s]) * 4096.f);
    *(i32x4*)(base + ((hb*4+g)<<10) + (l<<4)) = v;
  }
}

// standalone xg (prologue chunk 0 + sequential fallback), 8 waves
__global__ __launch_bounds__(512) void xg_kernel(const int* sent, const float* emb,
    const unsigned short* wih_p, const float* bias, int* xg, int k)
{
  xg_body(sent, emb, wih_p, bias, xg, k, blockIdx.y*256 + blockIdx.x, threadIdx.x);
}

// ---------------- fused: lstm chunk k (blocks 0-15, 16 waves) + xg k+1 -----
// 16 hidden/wave -> 4 waves/SIMD fills issue bubbles; xg enters through the
// i8-MFMA C-operand (int32), deleting the per-step unpack/convert VALU block.
__global__ __launch_bounds__(1024, 1) void fused_kernel(
    const int* sent, const float* emb, const unsigned short* wih_p, const float* bias,
    const int* xg_rd, int* xg_wr,
    const signed char* whh_p, const signed char* we_p,
    float* emis_f, float* emis_b, unsigned char* hsave, float* csave, int k)
{
  if (blockIdx.x >= 16) {
    if (threadIdx.x < 512 && k + 1 < NCHUNK)
      xg_body(sent, emb, wih_p, bias, xg_wr, k + 1, blockIdx.x - 16, threadIdx.x);
    return;
  }

  __shared__ char h_lds[8192];     // 2 x 4KB i8 h buffers, XOR-swizzled
  __shared__ char we_lds[8192];    // emission weights for this direction

  int id = blockIdx.x, d = id >> 3, nb = id & 7, bbase = nb*16;
  int w = threadIdx.x >> 6, l = threadIdx.x & 63, lg = l >> 4, lm = l & 15;
  float* emis = d ? emis_b : emis_f;
  bool ewave = (w < 2);            // emission on waves 0 (SIMD0), 1 (SIMD1)
  int nte = w & 1;

  // stage emission weights (8 KB for this direction)
  if (threadIdx.x < 512)
    ((u32x4*)we_lds)[threadIdx.x] = ((const u32x4*)we_p)[d*512 + threadIdx.x];

  // W_hh slice in registers: 16 frags x 4 regs = 64 VGPRs
  i32x4 wreg[16];
  const char* wbase = (const char*)whh_p + ((long)(d*16 + w) << 14);
  #pragma unroll
  for (int i = 0; i < 16; ++i)
    wreg[i] = *(const i32x4*)(wbase + (i << 10) + (l << 4));

  float c[4];
  if (k == 0) {
    for (int i = threadIdx.x; i < 2048; i += 1024) ((unsigned*)h_lds)[i] = 0u;
    #pragma unroll
    for (int i = 0; i < 4; ++i) c[i] = 0.f;
  } else {
    u32x4* hl = (u32x4*)(h_lds + 4096);   // read-buffer of step u=0
    const u32x4* hs = (const u32x4*)(hsave + (long)id*4096);
    if (threadIdx.x < 256) hl[threadIdx.x] = hs[threadIdx.x];
    const float* cs = csave + ((long)id*1024 + threadIdx.x)*4;
    #pragma unroll
    for (int i = 0; i < 4; ++i) c[i] = cs[i];
  }
  __syncthreads();

  int prev_t = (k == 0) ? -1 : (d ? (T_LEN - k*CHUNK) : (k*CHUNK - 1));

  for (int u = 0; u < CHUNK; ++u) {
    int ss = k*CHUNK + u;
    int t = d ? (T_LEN-1-ss) : ss;

    // acc init = int32 xg (issued early; MFMA C-operand)
    const char* xb = (const char*)xg_rd + (((long)(d*CHUNK + u)*8 + nb) << 16);
    i32x4 acc[4];
    #pragma unroll
    for (int g = 0; g < 4; ++g)
      acc[g] = *(const i32x4*)(xb + ((w*4+g)<<10) + (l<<4));

    // single barrier: prev step's h writes (other buffer) now visible
    asm volatile("s_waitcnt lgkmcnt(0)" ::: "memory");
    __builtin_amdgcn_s_barrier();

    const char* hr = h_lds + (((u & 1) ^ 1) << 12);   // read buffer
    char*       hw = h_lds + ((u & 1) << 12);         // write buffer

    // A-frags: 16 B/lane per K-64 group
    i32x4 a4[4];
    #pragma unroll
    for (int kq = 0; kq < 4; ++kq) {
      int off = (lm*256 + kq*64 + lg*16) ^ ((lm&7)<<4);
      a4[kq] = *(const i32x4*)(hr + off);
    }

    // emissions (waves 0,1): 4 i8 MFMAs for previous h
    i32x4 ea = {0,0,0,0};
    if (ewave && prev_t >= 0) {
      #pragma unroll
      for (int kq = 0; kq < 4; ++kq) {
        i32x4 ew = *(const i32x4*)(we_lds + ((nte*4 + kq) << 10) + (l << 4));
        ea = __builtin_amdgcn_mfma_i32_16x16x64_i8(a4[kq], ew, ea, 0,0,0);
      }
    }

    // main matvec: 16 i8 MFMAs, accumulating onto the xg init
    #pragma unroll
    for (int kq = 0; kq < 4; ++kq)
      #pragma unroll
      for (int g = 0; g < 4; ++g)
        acc[g] = __builtin_amdgcn_mfma_i32_16x16x64_i8(a4[kq], wreg[kq*4+g], acc[g], 0,0,0);

    // emissions store (de-scale 1/4096)
    if (ewave && prev_t >= 0) {
      int cc = nte*16 + lm;
      if (cc < NCLS) {
        #pragma unroll
        for (int r = 0; r < 4; ++r)
          emis[((long)prev_t*BATCH + bbase + lg*4 + r)*NCLS + cc] = (float)ea[r]*INV4096;
      }
    }

    // gates to log2 domain (one cvt+mul per value), then nonlinearities
    #pragma unroll
    for (int r = 0; r < 4; ++r) {
      float gi = (float)acc[0][r]*INV4096_LOG2E;
      float gf = (float)acc[1][r]*INV4096_LOG2E;
      float gg = (float)acc[2][r]*INV4096_LOG2E;
      float go = (float)acc[3][r]*INV4096_LOG2E;
      float si = sig2(gi);
      float sf = sig2(gf);
      float tg = tanh2(gg);
      float so = sig2(go);
      float cn = sf*c[r] + si*tg;
      c[r] = cn;
      float tc = 2.f*__builtin_amdgcn_rcpf(1.f + __builtin_amdgcn_exp2f(cn*NEG2LOG2E)) - 1.f;
      int m = lg*4 + r;
      int jj = w*16 + lm;
      int off = (m*256 + jj) ^ ((m&7)<<4);
      *(signed char*)(hw + off) = (signed char)__float2int_rn(so*tc*64.f);
    }
    prev_t = t;
  }

  asm volatile("s_waitcnt lgkmcnt(0)" ::: "memory");
  __builtin_amdgcn_s_barrier();
  // final h lives in buffer 1 (last write u=63 -> 63&1 = 1)

  if (k == NCHUNK-1) {
    if (ewave) {
      i32x4 a4[4];
      #pragma unroll
      for (int kq = 0; kq < 4; ++kq) {
        int off = (lm*256 + kq*64 + lg*16) ^ ((lm&7)<<4);
        a4[kq] = *(const i32x4*)(h_lds + 4096 + off);
      }
      i32x4 ea = {0,0,0,0};
      #pragma unroll
      for (int kq = 0; kq < 4; ++kq) {
        i32x4 ew = *(const i32x4*)(we_lds + ((nte*4 + kq) << 10) + (l << 4));
        ea = __builtin_amdgcn_mfma_i32_16x16x64_i8(a4[kq], ew, ea, 0,0,0);
      }
      int cc = nte*16 + lm;
      if (cc < NCLS) {
        #pragma unroll
        for (int r = 0; r < 4; ++r)
          emis[((long)prev_t*BATCH + bbase + lg*4 + r)*NCLS + cc] = (float)ea[r]*INV4096;
      }
    }
  } else {
    u32x4* hl = (u32x4*)(h_lds + 4096);
    u32x4* hs = (u32x4*)(hsave + (long)id*4096);
    if (threadIdx.x < 256) hs[threadIdx.x] = hl[threadIdx.x];
    float* cs = csave + ((long)id*1024 + threadIdx.x)*4;
    #pragma unroll
    for (int i = 0; i < 4; ++i) cs[i] = c[i];
  }
}

// ---------------- emissions fuse: emis_c = emis_f + emis_b + b_e ------------
__global__ __launch_bounds__(256) void efuse_kernel(const float* emis_f,
    const float* emis_b, const float* b_e, float* emis_c)
{
  int i = blockIdx.x*256 + threadIdx.x;
  if (i < T_LEN*BATCH*NCLS)
    emis_c[i] = emis_f[i] + emis_b[i] + b_e[i % NCLS];
}

// ---------------- CRF numerator -------------------------------------------
__global__ void num_kernel(const int* sent, const int* tags, const float* emis_c,
    const float* start_t, const float* end_t, const float* trans, float* num_buf)
{
  int b = blockIdx.x, l = threadIdx.x;   // 64 threads = 1 wave
  float acc = 0.f; int cnt = 0;
  for (int t = l; t < T_LEN; t += 64) {
    int tag = tags[t*BATCH + b];
    float E = emis_c[((long)t*BATCH+b)*NCLS + tag];
    int m = (sent[t*BATCH+b] != PADTOK) ? 1 : 0;
    cnt += m;
    if (t == 0) acc += start_t[tag] + E;
    else if (m) acc += trans[tags[(t-1)*BATCH + b]*NCLS + tag] + E;
  }
  #pragma unroll
  for (int off = 32; off; off >>= 1) { acc += __shfl_xor(acc, off); cnt += __shfl_xor(cnt, off); }
  if (l == 0) num_buf[b] = acc + end_t[tags[(cnt-1)*BATCH + b]];
}

// ---- CRF forward (denominator): readfirstlane ref + readlane/SGPR bcast ---
__global__ __launch_bounds__(64) void denom_kernel(const int* sent, const float* emis_c,
    const float* start_t, const float* end_t, const float* trans,
    const float* num_buf, float* llh)
{
  const float INVLN2 = 1.4426950408889634f;
  const float LN2 = 0.6931471805599453f;
  int l = threadIdx.x;
  bool valid = l < NCLS;
  int j = valid ? l : 0;
  int b = blockIdx.x;                     // 128 blocks, 1 row per wave

  float etr[NCLS];                        // E column j, linear domain
  #pragma unroll
  for (int i = 0; i < NCLS; ++i)
    etr[i] = __builtin_amdgcn_exp2f(trans[i*NCLS + j] * INVLN2);

  float S = (start_t[j] + emis_c[(long)b*NCLS + j]) * INVLN2;

  float e1 = emis_c[((long)1*BATCH + b)*NCLS + j];
  float e2 = emis_c[((long)2*BATCH + b)*NCLS + j];
  int m1 = sent[1*BATCH + b], m2 = sent[2*BATCH + b];

  for (int t = 1; t < T_LEN; ++t) {
    float e0 = e1; int m0 = m1;
    e1 = e2; m1 = m2;
    if (t + 2 < T_LEN) {
      e2 = emis_c[((long)(t+2)*BATCH + b)*NCLS + j];
      m2 = sent[(t+2)*BATCH + b];
    }
    float sref = __builtin_bit_cast(float,
        __builtin_amdgcn_readfirstlane(__builtin_bit_cast(int, S)));
    float qv = __builtin_amdgcn_exp2f(S - sref);
    float accs[5] = {0.f, 0.f, 0.f, 0.f, 0.f};
    #pragma unroll
    for (int i = 0; i < NCLS; ++i) {
      float qi = __builtin_bit_cast(float,
          __builtin_amdgcn_readlane(__builtin_bit_cast(int, qv), i));
      accs[i % 5] = fmaf(qi, etr[i], accs[i % 5]);
    }
    float dot = ((accs[0] + accs[1]) + (accs[2] + accs[3])) + accs[4];
    float nxt = sref + __builtin_amdgcn_logf(dot) + e0 * INVLN2;
    if (m0 != PADTOK) S = nxt;
  }

  float vf = valid ? (S + end_t[j] * INVLN2) : -1e30f;
  float mx = vf;
  #pragma unroll
  for (int off = 32; off; off >>= 1) mx = fmaxf(mx, __shfl_xor(mx, off));
  float ss = valid ? __builtin_amdgcn_exp2f(vf - mx) : 0.f;
  #pragma unroll
  for (int off = 32; off; off >>= 1) ss += __shfl_xor(ss, off);
  if (l == 0) llh[b] = num_buf[b] - (mx + __builtin_amdgcn_logf(ss)) * LN2;
}

__global__ void final_kernel(const float* llh, float* out) {
  __shared__ float red[2];
  int l = threadIdx.x;   // 128
  float v = llh[l];
  #pragma unroll
  for (int off = 32; off; off >>= 1) v += __shfl_xor(v, off);
  if ((l & 63) == 0) red[l >> 6] = v;
  __syncthreads();
  if (l == 0) out[0] = -(red[0] + red[1]);
}

extern "C" void kernel_launch(void* const* d_in, const int* in_sizes, int n_in,
                              void* d_out, int out_size, void* d_ws, size_t ws_size,
                              hipStream_t stream) {
  const int*   sent  = (const int*)d_in[0];
  const int*   tags  = (const int*)d_in[1];
  const float* emb   = (const float*)d_in[2];
  const float* wih_f = (const float*)d_in[3];
  const float* whh_f = (const float*)d_in[4];
  const float* bih_f = (const float*)d_in[5];
  const float* bhh_f = (const float*)d_in[6];
  const float* wih_b = (const float*)d_in[7];
  const float* whh_b = (const float*)d_in[8];
  const float* bih_b = (const float*)d_in[9];
  const float* bhh_b = (const float*)d_in[10];
  const float* W_e   = (const float*)d_in[11];
  const float* b_e   = (const float*)d_in[12];
  const float* st    = (const float*)d_in[13];
  const float* et    = (const float*)d_in[14];
  const float* tr    = (const float*)d_in[15];
  (void)in_sizes; (void)n_in; (void)out_size;

  const long SLOT = (long)2*CHUNK*BATCH*1024*4;   // 64 MiB per int32 xg slot

  char* ws = (char*)d_ws;
  unsigned short* wih_p  = (unsigned short*)ws; ws += (long)N_WPERM*2;      // 1 MiB
  signed char*    whh_p  = (signed char*)ws;    ws += (long)N_WPERM;        // 512 KiB
  signed char*    we_p   = (signed char*)ws;    ws += (long)N_WE;           // 16 KiB
  float*          bias   = (float*)ws;          ws += (long)N_BIAS*4;       // 8 KiB
  int*            xgr0   = (int*)ws;            ws += SLOT;                 // 64 MiB
  float*          emis_f = (float*)ws;          ws += (long)T_LEN*BATCH*NCLS*4;
  float*          emis_b = (float*)ws;          ws += (long)T_LEN*BATCH*NCLS*4;
  unsigned char*  hsave  = (unsigned char*)ws;  ws += (long)16*4096;
  float*          csave  = (float*)ws;          ws += (long)16*1024*4*4;    // 256 KiB
  float*          numb   = (float*)ws;          ws += 512;
  float*          llh    = (float*)ws;          ws += 512;
  int*            xgr1   = (int*)ws;            ws += SLOT;                 // 64 MiB (pipelined)
  float*          emis_c = (float*)xgr0;        // alias: slots dead after last lstm

  bool pipelined = ws_size >= (size_t)((char*)ws - (char*)d_ws);

  prep_kernel<<<4168, 256, 0, stream>>>(wih_f, whh_f, bih_f, bhh_f,
                                        wih_b, whh_b, bih_b, bhh_b, W_e,
                                        wih_p, whh_p, we_p, bias);
  if (pipelined) {
    dim3 g1(256, 2);
    xg_kernel<<<g1, 512, 0, stream>>>(sent, emb, wih_p, bias, xgr0, 0);
    for (int k = 0; k < NCHUNK; ++k) {
      int* rd = (k & 1) ? xgr1 : xgr0;
      int* wr = (k & 1) ? xgr0 : xgr1;
      int grid = (k + 1 < NCHUNK) ? 528 : 16;
      fused_kernel<<<grid, 1024, 0, stream>>>(sent, emb, wih_p, bias, rd, wr,
                                              whh_p, we_p, emis_f, emis_b, hsave, csave, k);
    }
  } else {
    for (int k = 0; k < NCHUNK; ++k) {
      dim3 g1(256, 2);
      xg_kernel<<<g1, 512, 0, stream>>>(sent, emb, wih_p, bias, xgr0, k);
      fused_kernel<<<16, 1024, 0, stream>>>(sent, emb, wih_p, bias, xgr0, xgr0,
                                            whh_p, we_p, emis_f, emis_b, hsave, csave, k);
    }
  }
  efuse_kernel<<<(T_LEN*BATCH*NCLS + 255)/256, 256, 0, stream>>>(emis_f, emis_b, b_e, emis_c);
  num_kernel<<<128, 64, 0, stream>>>(sent, tags, emis_c, st, et, tr, numb);
  denom_kernel<<<128, 64, 0, stream>>>(sent, emis_c, st, et, tr, numb, llh);
  final_kernel<<<1, 128, 0, stream>>>(llh, (float*)d_out);
}